// Round 23
// baseline (560.464 us; speedup 1.0000x reference)
//
#include <hip/hip_runtime.h>
#include <math.h>

#define B_   64
#define N_   512
#define E_   524288
#define BN_  32768
#define K1_  410
#define K2_  328
#define NK_  26240   // B_*K1_
#define KC_  25      // layer-1 K chunk

__device__ __forceinline__ float lrelu(float x) { return x > 0.f ? x : 0.2f * x; }

// ---------------------------------------------------------------- norms
__global__ __launch_bounds__(256) void norm_kernel(const float* __restrict__ p1,
                                                   const float* __restrict__ p2,
                                                   float* __restrict__ norms) {
    __shared__ float r1[256], r2[256];
    int t = threadIdx.x;
    float a = p1[t], b = p2[t];
    r1[t] = a * a; r2[t] = b * b;
    for (int o = 128; o > 0; o >>= 1) {
        __syncthreads();
        if (t < o) { r1[t] += r1[t + o]; r2[t] += r2[t + o]; }
    }
    __syncthreads();
    if (t == 0) { norms[0] = sqrtf(r1[0]); norms[1] = sqrtf(r2[0]); }
}

// ---------------------------------------------------------------- generic scan (exclusive) over NSEG counters
template <int NSEG>
__global__ __launch_bounds__(1024) void scan_kernel(int* __restrict__ cnt, int* __restrict__ offsets)
{
    __shared__ int part[1024];
    int t = threadIdx.x;
    const int CH = (NSEG + 1023) / 1024;
    int base = t * CH;
    int sum = 0;
    for (int i = 0; i < CH; ++i) { int gi = base + i; if (gi < NSEG) sum += cnt[gi]; }
    part[t] = sum;
    __syncthreads();
    for (int o = 1; o < 1024; o <<= 1) {
        int v = (t >= o) ? part[t - o] : 0;
        __syncthreads();
        part[t] += v;
        __syncthreads();
    }
    int run = (t == 0) ? 0 : part[t - 1];
    for (int i = 0; i < CH; ++i) {
        int gi = base + i;
        if (gi < NSEG) { offsets[gi] = run; run += cnt[gi]; cnt[gi] = 0; }
    }
    if (t == 1023) offsets[NSEG] = part[1023];
}

// ---------------------------------------------------------------- node-CSR (dst over ALL edges)
__global__ __launch_bounds__(256) void count_node_kernel(const int* __restrict__ dstG,
                                                         int* __restrict__ cnt_node)
{
    int e = blockIdx.x * blockDim.x + threadIdx.x;
    atomicAdd(&cnt_node[dstG[e]], 1);
}

// writes inverse permutation pos_e[e]=p AND forward map csr_e[p]=e
__global__ __launch_bounds__(256) void fill_node_kernel(const int* __restrict__ dstG,
                                                        const int* __restrict__ offs_node,
                                                        int* __restrict__ cnt_node,
                                                        int* __restrict__ pos_e,
                                                        int* __restrict__ csr_e)
{
    int e = blockIdx.x * blockDim.x + threadIdx.x;
    int d = dstG[e];
    int p = offs_node[d] + atomicAdd(&cnt_node[d], 1);
    pos_e[e] = p;
    csr_e[p] = e;
}

// ---------------------------------------------------------------- fused edge MLP (R16 measured-good form: 256 thr)
__global__ __launch_bounds__(256) void edge_mlp_kernel(
    const float* __restrict__ edge_attr, const int* __restrict__ srcG,
    const int* __restrict__ pos_e,
    const float* __restrict__ x,
    const float* __restrict__ W1, const float* __restrict__ b1,
    const float* __restrict__ W2, const float* __restrict__ b2,
    float* __restrict__ msg_sorted)
{
    __shared__ float bufAT[KC_][68];  // attr chunk, k-major
    __shared__ float w1cT[KC_][64];   // W1 chunk, k-major (linear i)
    __shared__ float ea1T[64][68];    // layer-1 out [col][edge], 272B rows
    __shared__ float w2s[64][32];
    __shared__ float b2s[32];
    __shared__ int   srcs[64], poss[64];

    int tid = threadIdx.x;
    int eb  = blockIdx.x * 64;

    if (tid < 64) { srcs[tid] = srcG[eb + tid]; poss[tid] = pos_e[eb + tid]; }
    for (int i = tid; i < 64 * 32; i += 256) w2s[i >> 5][i & 31] = W2[i];
    if (tid >= 192 && tid < 224) b2s[tid - 192] = b2[tid - 192];

    int tx = tid & 15, ty = tid >> 4;
    float b1v[4];
#pragma unroll
    for (int j = 0; j < 4; ++j) b1v[j] = b1[tx * 4 + j];

    // hoisted staging indices
    int attr_base[7], lds_a[7];
    bool valid[7];
#pragma unroll
    for (int u = 0; u < 7; ++u) {
        int i = tid + u * 256;
        valid[u] = (i < 1600);
        int e = i / 25, k = i - e * 25;
        attr_base[u] = (eb + e) * 100 + k;
        lds_a[u] = k * 68 + e;
    }
    float* bufA0 = &bufAT[0][0];
    float* w1l   = &w1cT[0][0];

    float acc[4][4] = {};

    float raA[7], raB[7], rw[7];
    auto issueA = [&](int kc, float (&ra)[7]) {
#pragma unroll
        for (int u = 0; u < 7; ++u)
            if (valid[u]) ra[u] = edge_attr[(size_t)(attr_base[u] + kc)];
    };
    auto issueW = [&](int kc) {
#pragma unroll
        for (int u = 0; u < 7; ++u) {
            int i = tid + u * 256;
            if (valid[u]) rw[u] = W1[(size_t)kc * 64 + i];
        }
    };
    auto lwriteA = [&](float (&ra)[7]) {
#pragma unroll
        for (int u = 0; u < 7; ++u)
            if (valid[u]) bufA0[lds_a[u]] = ra[u];
    };
    auto lwriteW = [&]() {
#pragma unroll
        for (int u = 0; u < 7; ++u) {
            int i = tid + u * 256;
            if (valid[u]) w1l[i] = rw[u];
        }
    };

    issueA(0, raA);
    issueW(0);
    issueA(KC_, raB);
    lwriteA(raA); lwriteW();
    __syncthreads();

#pragma unroll
    for (int c = 0; c < 4; ++c) {
        if (c == 0) issueA(2 * KC_, raA);
        if (c == 1) issueA(3 * KC_, raB);
        if (c < 3)  issueW((c + 1) * KC_);
#pragma unroll 5
        for (int k = 0; k < KC_; ++k) {
            float4 a4 = *(const float4*)&bufAT[k][ty * 4];
            float4 w4 = *(const float4*)&w1cT[k][tx * 4];
            float a[4] = { a4.x, a4.y, a4.z, a4.w };
            float w[4] = { w4.x, w4.y, w4.z, w4.w };
#pragma unroll
            for (int i = 0; i < 4; ++i)
#pragma unroll
                for (int j = 0; j < 4; ++j) acc[i][j] += a[i] * w[j];
        }
        if (c < 3) {
            __syncthreads();
            if ((c & 1) == 0) lwriteA(raB);
            else              lwriteA(raA);
            lwriteW();
            __syncthreads();
        }
    }
#pragma unroll
    for (int j = 0; j < 4; ++j) {
        float4 v;
        v.x = fmaxf(acc[0][j] + b1v[j], 0.f);
        v.y = fmaxf(acc[1][j] + b1v[j], 0.f);
        v.z = fmaxf(acc[2][j] + b1v[j], 0.f);
        v.w = fmaxf(acc[3][j] + b1v[j], 0.f);
        *(float4*)&ea1T[tx * 4 + j][ty * 4] = v;
    }
    __syncthreads();

    // ---- layer 2
    int e0 = (tid >> 3) * 2;       // even
    int c0 = (tid & 7) * 4;
    float acc2[2][4] = {};
    for (int k = 0; k < 64; ++k) {
        float2 a2 = *(const float2*)&ea1T[k][e0];
        float4 w4 = *(const float4*)&w2s[k][c0];
        float w[4] = { w4.x, w4.y, w4.z, w4.w };
#pragma unroll
        for (int j = 0; j < 4; ++j) {
            acc2[0][j] += a2.x * w[j]; acc2[1][j] += a2.y * w[j];
        }
    }
#pragma unroll
    for (int r = 0; r < 2; ++r) {
        int e = e0 + r, s = srcs[e];
        const float4 xv = *(const float4*)(x + (size_t)s * 32 + c0);
        float xa[4] = { xv.x, xv.y, xv.z, xv.w };
        float4 m;
        m.x = fmaxf(xa[0] + fmaxf(acc2[r][0] + b2s[c0 + 0], 0.f), 0.f);
        m.y = fmaxf(xa[1] + fmaxf(acc2[r][1] + b2s[c0 + 1], 0.f), 0.f);
        m.z = fmaxf(xa[2] + fmaxf(acc2[r][2] + b2s[c0 + 2], 0.f), 0.f);
        m.w = fmaxf(xa[3] + fmaxf(acc2[r][3] + b2s[c0 + 3], 0.f), 0.f);
        *(float4*)(msg_sorted + (size_t)poss[e] * 32 + c0) = m;
    }
}

// ---------------------------------------------------------------- segmented sum over dst-sorted msg rows
__global__ __launch_bounds__(256) void segsum_kernel(const float* __restrict__ msg_sorted,
                                                     const int* __restrict__ offs_n,
                                                     float* __restrict__ agg)
{
    int wid  = (blockIdx.x * blockDim.x + threadIdx.x) >> 6;
    int lane = threadIdx.x & 63;
    if (wid >= BN_) return;
    int off0 = offs_n[wid], off1 = offs_n[wid + 1];
    int col = lane & 31, rr = lane >> 5;
    float sum = 0.f;
    for (int j = off0 + rr; j < off1; j += 2)
        sum += msg_sorted[(size_t)j * 32 + col];
    sum += __shfl_xor(sum, 32);
    if (lane < 32) agg[(size_t)wid * 32 + col] = sum;
}

// ---------------------------------------------------------------- 128x128 tiled GEMM, 8x8 microtile, LDS double-buffer
// (no min-wave launch_bounds cap: R8's spill was the cap, not the dbuf)
template <int ACT, bool HASBIAS, bool HASA2, bool GATHER, bool SCORES, bool ATTC>
__global__ __launch_bounds__(256) void gemm_tile128(
    const float* __restrict__ A, const float* __restrict__ A2,
    const int* __restrict__ rowidx, const float* __restrict__ rowscale,
    const float* __restrict__ W, const float* __restrict__ bias,
    float* __restrict__ C, int M, int N, int K,
    const float* __restrict__ pvec, float* __restrict__ pout,
    const float* __restrict__ av_src, const float* __restrict__ av_dst,
    float* __restrict__ ao_src, float* __restrict__ ao_dst)
{
    __shared__ float As[2][16][132];
    __shared__ float Ws[2][16][132];
    int tid = threadIdx.x;
    int tx = tid & 15, ty = tid >> 4;
    int mb = blockIdx.y * 128, nb = blockIdx.x * 128;
    float acc[8][8] = {};

    int am = tid & 127;
    int ak = (tid >> 7) * 8;
    int wk = tid >> 4;
    int wn = (tid & 15) * 8;

    int   arow  = mb + am;
    float ascal = 1.f;
    if (GATHER) { ascal = rowscale[arow]; arow = rowidx[arow]; }

    float4 av0, av1, wv0, wv1;
    auto gload = [&](int kt) {
        const float* pa = A + (size_t)arow * K + kt + ak;
        av0 = *(const float4*)(pa);
        av1 = *(const float4*)(pa + 4);
        if (HASA2) {
            const float* pb = A2 + (size_t)arow * K + kt + ak;
            float4 u0 = *(const float4*)(pb);
            float4 u1 = *(const float4*)(pb + 4);
            av0.x += u0.x; av0.y += u0.y; av0.z += u0.z; av0.w += u0.w;
            av1.x += u1.x; av1.y += u1.y; av1.z += u1.z; av1.w += u1.w;
        }
        if (GATHER) {
            av0.x *= ascal; av0.y *= ascal; av0.z *= ascal; av0.w *= ascal;
            av1.x *= ascal; av1.y *= ascal; av1.z *= ascal; av1.w *= ascal;
        }
        const float* pw = W + (size_t)(kt + wk) * N + nb + wn;
        wv0 = *(const float4*)(pw);
        wv1 = *(const float4*)(pw + 4);
    };
    auto swrite = [&](int buf) {
        As[buf][ak + 0][am] = av0.x; As[buf][ak + 1][am] = av0.y;
        As[buf][ak + 2][am] = av0.z; As[buf][ak + 3][am] = av0.w;
        As[buf][ak + 4][am] = av1.x; As[buf][ak + 5][am] = av1.y;
        As[buf][ak + 6][am] = av1.z; As[buf][ak + 7][am] = av1.w;
        *(float4*)&Ws[buf][wk][wn]     = wv0;
        *(float4*)&Ws[buf][wk][wn + 4] = wv1;
    };

    gload(0);
    swrite(0);
    __syncthreads();
    int nt = K / 16;
    for (int t = 0; t < nt; ++t) {
        int cur = t & 1;
        if (t + 1 < nt) gload((t + 1) * 16);   // next tile in flight under compute
#pragma unroll
        for (int k2 = 0; k2 < 16; ++k2) {
            float4 a0 = *(const float4*)&As[cur][k2][ty * 8];
            float4 a1 = *(const float4*)&As[cur][k2][ty * 8 + 4];
            float4 w0 = *(const float4*)&Ws[cur][k2][tx * 4];
            float4 w1 = *(const float4*)&Ws[cur][k2][64 + tx * 4];
            float a[8] = { a0.x, a0.y, a0.z, a0.w, a1.x, a1.y, a1.z, a1.w };
            float w[8] = { w0.x, w0.y, w0.z, w0.w, w1.x, w1.y, w1.z, w1.w };
#pragma unroll
            for (int i = 0; i < 8; ++i)
#pragma unroll
                for (int j = 0; j < 8; ++j) acc[i][j] += a[i] * w[j];
        }
        if (t + 1 < nt) {
            swrite(cur ^ 1);
            __syncthreads();
        }
    }
    int col0 = nb + tx * 4, col1 = nb + 64 + tx * 4;
    int hd0 = col0 >> 6, hd1 = col1 >> 6;
#pragma unroll
    for (int i = 0; i < 8; ++i) {
        int m = mb + ty * 8 + i;
        float r[8];
#pragma unroll
        for (int j = 0; j < 4; ++j) {
            float v = acc[i][j];
            if (HASBIAS) v += bias[col0 + j];
            if (ACT == 1) v = fmaxf(v, 0.f);
            r[j] = v;
        }
#pragma unroll
        for (int j = 4; j < 8; ++j) {
            float v = acc[i][j];
            if (HASBIAS) v += bias[col1 + j - 4];
            if (ACT == 1) v = fmaxf(v, 0.f);
            r[j] = v;
        }
        float4 o0 = { r[0], r[1], r[2], r[3] };
        float4 o1 = { r[4], r[5], r[6], r[7] };
        *(float4*)&C[(size_t)m * N + col0] = o0;
        *(float4*)&C[(size_t)m * N + col1] = o1;

        if (SCORES) {
            float d = 0.f;
#pragma unroll
            for (int j = 0; j < 4; ++j) d += r[j] * pvec[col0 + j];
#pragma unroll
            for (int j = 4; j < 8; ++j) d += r[j] * pvec[col1 + j - 4];
#pragma unroll
            for (int o = 1; o < 16; o <<= 1) d += __shfl_xor(d, o);
            if (tx == 0) atomicAdd(&pout[m], d);
        }
        if (ATTC) {
            float sA = 0.f, sB = 0.f, dA = 0.f, dB = 0.f;
#pragma unroll
            for (int j = 0; j < 4; ++j) {
                int w0i = hd0 * 64 + ((col0 & 63) + j);
                int w1i = hd1 * 64 + ((col1 & 63) + j);
                sA += r[j] * av_src[w0i];   dA += r[j] * av_dst[w0i];
                sB += r[j + 4] * av_src[w1i]; dB += r[j + 4] * av_dst[w1i];
            }
#pragma unroll
            for (int o = 1; o < 16; o <<= 1) {
                sA += __shfl_xor(sA, o); sB += __shfl_xor(sB, o);
                dA += __shfl_xor(dA, o); dB += __shfl_xor(dB, o);
            }
            if (tx == 0) {
                atomicAdd(&ao_src[m * 4 + hd0], sA);
                atomicAdd(&ao_src[m * 4 + hd1], sB);
                atomicAdd(&ao_dst[m * 4 + hd0], dA);
                atomicAdd(&ao_dst[m * 4 + hd1], dB);
            }
        }
    }
}

// ---------------------------------------------------------------- bitonic sort (512, descending, idx-asc tiebreak)
__device__ void bitonic_desc512(float* val, int* idx, int t) {
    for (int k = 2; k <= 512; k <<= 1) {
        for (int j = k >> 1; j > 0; j >>= 1) {
            __syncthreads();
            int ixj = t ^ j;
            if (ixj > t) {
                float v0 = val[t], v1 = val[ixj];
                int   i0 = idx[t], i1 = idx[ixj];
                bool before = (v0 > v1) || (v0 == v1 && i0 < i1);
                bool dir = ((t & k) == 0);
                bool doswap = dir ? (!before) : before;
                if (doswap) { val[t] = v1; val[ixj] = v0; idx[t] = i1; idx[ixj] = i0; }
            }
        }
    }
    __syncthreads();
}

// sorts RAW scores (tanh monotonic); applies tanh(s/norm) only to selected
__global__ __launch_bounds__(512) void topk1_kernel(const float* __restrict__ s,
                                                    const float* __restrict__ norms,
                                                    float* __restrict__ topval,
                                                    int* __restrict__ topnode,
                                                    int* __restrict__ kept,
                                                    int* __restrict__ newid)
{
    __shared__ float val[512];
    __shared__ int   idx[512];
    int b = blockIdx.x, t = threadIdx.x;
    val[t] = s[b * N_ + t]; idx[t] = t;
    bitonic_desc512(val, idx, t);
    if (t < K1_) {
        int node = b * N_ + idx[t];
        int orow = b * K1_ + t;
        topnode[orow] = node;
        topval[orow]  = tanhf(val[t] / norms[0]);
        kept[node]  = 1;
        newid[node] = orow;
    }
}

// ---------------------------------------------------------------- readout 1 (gathered): 256 blocks, 16 rowgroups
__global__ __launch_bounds__(1024) void readout1_kernel(const float* __restrict__ h,
                                                        const int* __restrict__ topnode,
                                                        const float* __restrict__ topval,
                                                        float* __restrict__ zbuf)
{
    __shared__ float rmx[1024], rsm[1024];
    int b = blockIdx.x >> 2, cg = blockIdx.x & 3;
    int tid = threadIdx.x;
    int cl = tid & 63, rg = tid >> 6;
    int c = cg * 64 + cl;
    float mx = -INFINITY, sm = 0.f;
    for (int j = rg; j < K1_; j += 16) {
        int row = topnode[b * K1_ + j];
        float v = h[(size_t)row * 256 + c] * topval[b * K1_ + j];
        mx = fmaxf(mx, v); sm += v;
    }
    rmx[tid] = mx; rsm[tid] = sm;
    __syncthreads();
    if (tid < 512) { rmx[tid] = fmaxf(rmx[tid], rmx[tid + 512]); rsm[tid] += rsm[tid + 512]; }
    __syncthreads();
    if (tid < 256) { rmx[tid] = fmaxf(rmx[tid], rmx[tid + 256]); rsm[tid] += rsm[tid + 256]; }
    __syncthreads();
    if (tid < 128) { rmx[tid] = fmaxf(rmx[tid], rmx[tid + 128]); rsm[tid] += rsm[tid + 128]; }
    __syncthreads();
    if (tid < 64) {
        zbuf[b * 512 + c]       = fmaxf(rmx[tid], rmx[tid + 64]);
        zbuf[b * 512 + 256 + c] = (rsm[tid] + rsm[tid + 64]) / (float)K1_;
    }
}

// ---------------------------------------------------------------- GAT aggregation via node-CSR + kept filter
__global__ __launch_bounds__(256) void gat_agg_kernel(const float* __restrict__ xl,
                                                      const float* __restrict__ a_src,
                                                      const float* __restrict__ a_dst,
                                                      const int* __restrict__ tnode,
                                                      const int* __restrict__ offs_n,
                                                      const int* __restrict__ csr_e,
                                                      const int* __restrict__ srcG,
                                                      const int* __restrict__ kept,
                                                      const int* __restrict__ newid,
                                                      const float* __restrict__ gat_b,
                                                      const float* __restrict__ pool2_w,
                                                      float* __restrict__ g,
                                                      float* __restrict__ s2)
{
    int wid  = (blockIdx.x * blockDim.x + threadIdx.x) >> 6;
    int lane = threadIdx.x & 63;
    if (wid >= NK_) return;
    int orig = tnode[wid];
    int off0 = offs_n[orig], off1 = offs_n[orig + 1];

    float4 ad = *(const float4*)(a_dst + (size_t)wid * 4);
    float4 asf = *(const float4*)(a_src + (size_t)wid * 4);
    float adv[4] = { ad.x, ad.y, ad.z, ad.w };
    float lsf[4] = { lrelu(asf.x + ad.x), lrelu(asf.y + ad.y),
                     lrelu(asf.z + ad.z), lrelu(asf.w + ad.w) };

    float den[4] = {};
    float acc[4] = {};
    int src_nxt = (off0 < off1) ? srcG[csr_e[off0]] : 0;
    for (int p = off0; p < off1; ++p) {
        int srcn = src_nxt;
        if (p + 1 < off1) src_nxt = srcG[csr_e[p + 1]];   // prefetch next chain
        if (!kept[srcn]) continue;       // wave-uniform branch
        int s1 = newid[srcn];
        float4 a1 = *(const float4*)(a_src + (size_t)s1 * 4);
        float av1[4] = { a1.x, a1.y, a1.z, a1.w };
#pragma unroll
        for (int r = 0; r < 4; ++r) {
            float w1 = expf(fminf(lrelu(av1[r] + adv[r]), 80.f));
            den[r] += w1;
            acc[r] += w1 * xl[(size_t)s1 * 256 + r * 64 + lane];
        }
    }
    float gv[4];
#pragma unroll
    for (int r = 0; r < 4; ++r) {
        float ws = expf(fminf(lsf[r], 80.f));
        den[r] += ws;
        acc[r] = (acc[r] + ws * xl[(size_t)wid * 256 + r * 64 + lane]) / den[r];
        int d = r * 64 + lane;
        gv[r] = fmaxf(acc[r] + gat_b[d], 0.f);
        g[(size_t)wid * 256 + d] = gv[r];
    }
    float dot = 0.f;
#pragma unroll
    for (int r = 0; r < 4; ++r) dot += gv[r] * pool2_w[r * 64 + lane];
    for (int o = 32; o > 0; o >>= 1) dot += __shfl_xor(dot, o);
    if (lane == 0) s2[wid] = dot;   // raw; tanh deferred (monotonic)
}

// ---------------------------------------------------------------- topk2 sort (64 blocks); tanh applied to selected
__global__ __launch_bounds__(512) void topk2_sort_kernel(const float* __restrict__ s2,
                                                         const float* __restrict__ norms,
                                                         int* __restrict__ t2row,
                                                         float* __restrict__ t2val)
{
    __shared__ float val[512];
    __shared__ int   idx[512];
    int b = blockIdx.x, t = threadIdx.x;
    val[t] = (t < K1_) ? s2[b * K1_ + t] : -INFINITY;
    idx[t] = t;
    bitonic_desc512(val, idx, t);
    if (t < K2_) {
        t2row[b * K2_ + t] = b * K1_ + idx[t];
        t2val[b * K2_ + t] = tanhf(val[t] / norms[1]);
    }
}

// ---------------------------------------------------------------- readout 2
__global__ __launch_bounds__(512) void readout2_kernel(const float* __restrict__ g,
                                                       const int* __restrict__ t2row,
                                                       const float* __restrict__ t2val,
                                                       float* __restrict__ zbuf)
{
    __shared__ float rmx[512], rsm[512];
    int b = blockIdx.x >> 2, cg = blockIdx.x & 3;
    int tid = threadIdx.x;
    int cl = tid & 63, rg = tid >> 6;
    int c = cg * 64 + cl;
    float mx = -INFINITY, sm = 0.f;
    for (int j = rg; j < K2_; j += 8) {
        int row = t2row[b * K2_ + j];
        float v = g[(size_t)row * 256 + c] * t2val[b * K2_ + j];
        mx = fmaxf(mx, v); sm += v;
    }
    rmx[tid] = mx; rsm[tid] = sm;
    __syncthreads();
    if (tid < 256) { rmx[tid] = fmaxf(rmx[tid], rmx[tid + 256]); rsm[tid] += rsm[tid + 256]; }
    __syncthreads();
    if (tid < 128) { rmx[tid] = fmaxf(rmx[tid], rmx[tid + 128]); rsm[tid] += rsm[tid + 128]; }
    __syncthreads();
    if (tid < 64) {
        zbuf[b * 512 + c]       += fmaxf(rmx[tid], rmx[tid + 64]);
        zbuf[b * 512 + 256 + c] += (rsm[tid] + rsm[tid + 64]) / (float)K2_;
    }
}

// ---------------------------------------------------------------- head
__global__ __launch_bounds__(128) void head_kernel(const float* __restrict__ zbuf,
                                                   const float* __restrict__ l1w, const float* __restrict__ l1b,
                                                   const float* __restrict__ l2w, const float* __restrict__ l2b,
                                                   const float* __restrict__ l3w, const float* __restrict__ l3b,
                                                   float* __restrict__ out)
{
    __shared__ float zs[512];
    __shared__ float h1s[128];
    __shared__ float h2s[64];
    __shared__ float os[2];
    int b = blockIdx.x, t = threadIdx.x;
    for (int i = t; i < 512; i += 128) zs[i] = zbuf[b * 512 + i];
    __syncthreads();
    float acc = l1b[t];
    for (int k = 0; k < 512; ++k) acc += zs[k] * l1w[k * 128 + t];
    h1s[t] = fmaxf(acc, 0.f);
    __syncthreads();
    if (t < 64) {
        float a2 = l2b[t];
        for (int k = 0; k < 128; ++k) a2 += h1s[k] * l2w[k * 64 + t];
        h2s[t] = fmaxf(a2, 0.f);
    }
    __syncthreads();
    if (t < 2) {
        float a3 = l3b[t];
        for (int k = 0; k < 64; ++k) a3 += h2s[k] * l3w[k * 2 + t];
        os[t] = a3;
    }
    __syncthreads();
    if (t == 0) {
        float m = fmaxf(os[0], os[1]);
        float lse = m + logf(expf(os[0] - m) + expf(os[1] - m));
        out[b * 2 + 0] = os[0] - lse;
        out[b * 2 + 1] = os[1] - lse;
    }
}

// ================================================================ launch
extern "C" void kernel_launch(void* const* d_in, const int* in_sizes, int n_in,
                              void* d_out, int out_size, void* d_ws, size_t ws_size,
                              hipStream_t stream)
{
    const float* x         = (const float*)d_in[0];
    const int*   eidx      = (const int*)d_in[1];
    const float* edge_attr = (const float*)d_in[3];
    const float* dec1_w    = (const float*)d_in[4];
    const float* dec1_b    = (const float*)d_in[5];
    const float* dec2_w    = (const float*)d_in[6];
    const float* dec2_b    = (const float*)d_in[7];
    const float* mlp1_w    = (const float*)d_in[8];
    const float* mlp1_b    = (const float*)d_in[9];
    const float* mlp2_w    = (const float*)d_in[10];
    const float* mlp2_b    = (const float*)d_in[11];
    const float* pool1_w   = (const float*)d_in[12];
    const float* gat_w     = (const float*)d_in[13];
    const float* att_src   = (const float*)d_in[14];
    const float* att_dst   = (const float*)d_in[15];
    const float* gat_b     = (const float*)d_in[16];
    const float* pool2_w   = (const float*)d_in[17];
    const float* lin1_w    = (const float*)d_in[18];
    const float* lin1_b    = (const float*)d_in[19];
    const float* lin2_w    = (const float*)d_in[20];
    const float* lin2_b    = (const float*)d_in[21];
    const float* lin3_w    = (const float*)d_in[22];
    const float* lin3_b    = (const float*)d_in[23];
    const int* srcG = eidx;
    const int* dstG = eidx + E_;
    float* out = (float*)d_out;

    // ---- workspace layout (zeroed prefix: cnt_node, kept, s, a_src, a_dst)
    char* base = (char*)d_ws;
    size_t o = 0;
    auto alloc = [&](size_t bytes) { size_t r = o; o = (o + bytes + 255) & ~(size_t)255; return r; };
    size_t cntn_off   = alloc((size_t)BN_ * 4);
    size_t kept_off   = alloc((size_t)BN_ * 4);
    size_t s_off      = alloc((size_t)BN_ * 4);        // scores1 accum; also s2
    size_t asrc_off   = alloc((size_t)NK_ * 4 * 4);
    size_t adst_off   = alloc((size_t)NK_ * 4 * 4);
    size_t zero_bytes = o;
    size_t agg_off    = alloc((size_t)BN_ * 32 * 4);   // overwritten by segsum (no zeroing)
    size_t newid_off  = alloc((size_t)BN_ * 4);
    size_t offsn_off  = alloc((size_t)(BN_ + 1) * 4);
    size_t pos_off    = alloc((size_t)E_ * 4);
    size_t csre_off   = alloc((size_t)E_ * 4);
    size_t h_off      = alloc((size_t)BN_ * 256 * 4);  // also g; msg_sorted aliases region
    size_t hp_off     = alloc((size_t)NK_ * 256 * 4);  // aliasing headroom for msg
    size_t xl_off     = alloc((size_t)NK_ * 256 * 4);  // also t1
    size_t tnode_off  = alloc((size_t)NK_ * 4);        // also t2row
    size_t tval_off   = alloc((size_t)NK_ * 4);        // also t2val
    size_t zbuf_off   = alloc((size_t)B_ * 512 * 4);
    size_t norm_off   = alloc(256);
    if (o > ws_size) return;

    int*   cnt_node = (int*)  (base + cntn_off);
    int*   kept     = (int*)  (base + kept_off);
    float* s        = (float*)(base + s_off);
    float* a_src    = (float*)(base + asrc_off);
    float* a_dst    = (float*)(base + adst_off);
    float* agg      = (float*)(base + agg_off);
    int*   newid    = (int*)  (base + newid_off);
    int*   offs_n   = (int*)  (base + offsn_off);
    int*   pos_e    = (int*)  (base + pos_off);
    int*   csr_e    = (int*)  (base + csre_off);
    float* h        = (float*)(base + h_off);
    float* g        = h;
    float* msg      = h;                                // [E_,32] aliases h..xl (dead before MLP1)
    float* xl       = (float*)(base + xl_off);
    float* t1       = xl;
    int*   tnode    = (int*)  (base + tnode_off);
    float* tval     = (float*)(base + tval_off);
    float* zbuf     = (float*)(base + zbuf_off);
    float* norms    = (float*)(base + norm_off);

    hipMemsetAsync(d_ws, 0, zero_bytes, stream);

    norm_kernel<<<1, 256, 0, stream>>>(pool1_w, pool2_w, norms);

    // node-CSR over ALL edges -> pos_e (inverse) + csr_e (forward)
    count_node_kernel<<<E_ / 256, 256, 0, stream>>>(dstG, cnt_node);
    scan_kernel<BN_><<<1, 1024, 0, stream>>>(cnt_node, offs_n);
    fill_node_kernel<<<E_ / 256, 256, 0, stream>>>(dstG, offs_n, cnt_node, pos_e, csr_e);

    // edge MLP in natural order (256 thr/block, R16 form), msg rows written dst-sorted
    edge_mlp_kernel<<<E_ / 64, 256, 0, stream>>>(edge_attr, srcG, pos_e, x,
                                                 dec1_w, dec1_b, dec2_w, dec2_b, msg);
    segsum_kernel<<<BN_ / 4, 256, 0, stream>>>(msg, offs_n, agg);

    // MLP1: t1 = relu((x+agg) @ mlp1_w + b)
    gemm_tile128<1, true, true, false, false, false><<<dim3(1, BN_ / 128), 256, 0, stream>>>(
        x, agg, nullptr, nullptr, mlp1_w, mlp1_b, t1, BN_, 128, 32,
        nullptr, nullptr, nullptr, nullptr, nullptr, nullptr);
    // MLP2: h = relu(t1 @ mlp2_w + b) + fused scores1 partial dots into s
    gemm_tile128<1, true, false, false, true, false><<<dim3(2, BN_ / 128), 256, 0, stream>>>(
        t1, nullptr, nullptr, nullptr, mlp2_w, mlp2_b, h, BN_, 256, 128,
        pool1_w, s, nullptr, nullptr, nullptr, nullptr);

    topk1_kernel<<<B_, 512, 0, stream>>>(s, norms, tval, tnode, kept, newid);
    readout1_kernel<<<B_ * 4, 1024, 0, stream>>>(h, tnode, tval, zbuf);

    // GAT transform with fused top-k gather + fused attcoef partials
    gemm_tile128<0, false, false, true, false, true><<<dim3(2, NK_ / 128), 256, 0, stream>>>(
        h, nullptr, tnode, tval, gat_w, nullptr, xl, NK_, 256, 256,
        nullptr, nullptr, att_src, att_dst, a_src, a_dst);

    // GAT aggregation via node-CSR + kept filter; raw s2
    gat_agg_kernel<<<NK_ / 4, 256, 0, stream>>>(xl, a_src, a_dst, tnode, offs_n, csr_e,
                                                srcG, kept, newid, gat_b, pool2_w, g, s);

    topk2_sort_kernel<<<B_, 512, 0, stream>>>(s, norms, tnode, tval);
    readout2_kernel<<<B_ * 4, 512, 0, stream>>>(g, tnode, tval, zbuf);

    head_kernel<<<B_, 128, 0, stream>>>(zbuf, lin1_w, lin1_b, lin2_w, lin2_b,
                                        lin3_w, lin3_b, out);
}

// Round 24
// 520.537 us; speedup vs baseline: 1.0767x; 1.0767x over previous
//
#include <hip/hip_runtime.h>
#include <math.h>

#define B_   64
#define N_   512
#define E_   524288
#define BN_  32768
#define K1_  410
#define K2_  328
#define NK_  26240   // B_*K1_
#define KC_  25      // layer-1 K chunk

__device__ __forceinline__ float lrelu(float x) { return x > 0.f ? x : 0.2f * x; }

// ---------------------------------------------------------------- norms
__global__ __launch_bounds__(256) void norm_kernel(const float* __restrict__ p1,
                                                   const float* __restrict__ p2,
                                                   float* __restrict__ norms) {
    __shared__ float r1[256], r2[256];
    int t = threadIdx.x;
    float a = p1[t], b = p2[t];
    r1[t] = a * a; r2[t] = b * b;
    for (int o = 128; o > 0; o >>= 1) {
        __syncthreads();
        if (t < o) { r1[t] += r1[t + o]; r2[t] += r2[t + o]; }
    }
    __syncthreads();
    if (t == 0) { norms[0] = sqrtf(r1[0]); norms[1] = sqrtf(r2[0]); }
}

// ---------------------------------------------------------------- generic scan (exclusive) over NSEG counters
template <int NSEG>
__global__ __launch_bounds__(1024) void scan_kernel(int* __restrict__ cnt, int* __restrict__ offsets)
{
    __shared__ int part[1024];
    int t = threadIdx.x;
    const int CH = (NSEG + 1023) / 1024;
    int base = t * CH;
    int sum = 0;
    for (int i = 0; i < CH; ++i) { int gi = base + i; if (gi < NSEG) sum += cnt[gi]; }
    part[t] = sum;
    __syncthreads();
    for (int o = 1; o < 1024; o <<= 1) {
        int v = (t >= o) ? part[t - o] : 0;
        __syncthreads();
        part[t] += v;
        __syncthreads();
    }
    int run = (t == 0) ? 0 : part[t - 1];
    for (int i = 0; i < CH; ++i) {
        int gi = base + i;
        if (gi < NSEG) { offsets[gi] = run; run += cnt[gi]; cnt[gi] = 0; }
    }
    if (t == 1023) offsets[NSEG] = part[1023];
}

// ---------------------------------------------------------------- node-CSR (dst over ALL edges)
__global__ __launch_bounds__(256) void count_node_kernel(const int* __restrict__ dstG,
                                                         int* __restrict__ cnt_node)
{
    int e = blockIdx.x * blockDim.x + threadIdx.x;
    atomicAdd(&cnt_node[dstG[e]], 1);
}

// writes inverse permutation pos_e[e]=p AND forward map csr_e[p]=e
__global__ __launch_bounds__(256) void fill_node_kernel(const int* __restrict__ dstG,
                                                        const int* __restrict__ offs_node,
                                                        int* __restrict__ cnt_node,
                                                        int* __restrict__ pos_e,
                                                        int* __restrict__ csr_e)
{
    int e = blockIdx.x * blockDim.x + threadIdx.x;
    int d = dstG[e];
    int p = offs_node[d] + atomicAdd(&cnt_node[d], 1);
    pos_e[e] = p;
    csr_e[p] = e;
}

// ---------------------------------------------------------------- fused edge MLP (R16 measured-good form: 256 thr)
__global__ __launch_bounds__(256) void edge_mlp_kernel(
    const float* __restrict__ edge_attr, const int* __restrict__ srcG,
    const int* __restrict__ pos_e,
    const float* __restrict__ x,
    const float* __restrict__ W1, const float* __restrict__ b1,
    const float* __restrict__ W2, const float* __restrict__ b2,
    float* __restrict__ msg_sorted)
{
    __shared__ float bufAT[KC_][68];  // attr chunk, k-major
    __shared__ float w1cT[KC_][64];   // W1 chunk, k-major (linear i)
    __shared__ float ea1T[64][68];    // layer-1 out [col][edge], 272B rows
    __shared__ float w2s[64][32];
    __shared__ float b2s[32];
    __shared__ int   srcs[64], poss[64];

    int tid = threadIdx.x;
    int eb  = blockIdx.x * 64;

    if (tid < 64) { srcs[tid] = srcG[eb + tid]; poss[tid] = pos_e[eb + tid]; }
    for (int i = tid; i < 64 * 32; i += 256) w2s[i >> 5][i & 31] = W2[i];
    if (tid >= 192 && tid < 224) b2s[tid - 192] = b2[tid - 192];

    int tx = tid & 15, ty = tid >> 4;
    float b1v[4];
#pragma unroll
    for (int j = 0; j < 4; ++j) b1v[j] = b1[tx * 4 + j];

    // hoisted staging indices
    int attr_base[7], lds_a[7];
    bool valid[7];
#pragma unroll
    for (int u = 0; u < 7; ++u) {
        int i = tid + u * 256;
        valid[u] = (i < 1600);
        int e = i / 25, k = i - e * 25;
        attr_base[u] = (eb + e) * 100 + k;
        lds_a[u] = k * 68 + e;
    }
    float* bufA0 = &bufAT[0][0];
    float* w1l   = &w1cT[0][0];

    float acc[4][4] = {};

    float raA[7], raB[7], rw[7];
    auto issueA = [&](int kc, float (&ra)[7]) {
#pragma unroll
        for (int u = 0; u < 7; ++u)
            if (valid[u]) ra[u] = edge_attr[(size_t)(attr_base[u] + kc)];
    };
    auto issueW = [&](int kc) {
#pragma unroll
        for (int u = 0; u < 7; ++u) {
            int i = tid + u * 256;
            if (valid[u]) rw[u] = W1[(size_t)kc * 64 + i];
        }
    };
    auto lwriteA = [&](float (&ra)[7]) {
#pragma unroll
        for (int u = 0; u < 7; ++u)
            if (valid[u]) bufA0[lds_a[u]] = ra[u];
    };
    auto lwriteW = [&]() {
#pragma unroll
        for (int u = 0; u < 7; ++u) {
            int i = tid + u * 256;
            if (valid[u]) w1l[i] = rw[u];
        }
    };

    issueA(0, raA);
    issueW(0);
    issueA(KC_, raB);
    lwriteA(raA); lwriteW();
    __syncthreads();

#pragma unroll
    for (int c = 0; c < 4; ++c) {
        if (c == 0) issueA(2 * KC_, raA);
        if (c == 1) issueA(3 * KC_, raB);
        if (c < 3)  issueW((c + 1) * KC_);
#pragma unroll 5
        for (int k = 0; k < KC_; ++k) {
            float4 a4 = *(const float4*)&bufAT[k][ty * 4];
            float4 w4 = *(const float4*)&w1cT[k][tx * 4];
            float a[4] = { a4.x, a4.y, a4.z, a4.w };
            float w[4] = { w4.x, w4.y, w4.z, w4.w };
#pragma unroll
            for (int i = 0; i < 4; ++i)
#pragma unroll
                for (int j = 0; j < 4; ++j) acc[i][j] += a[i] * w[j];
        }
        if (c < 3) {
            __syncthreads();
            if ((c & 1) == 0) lwriteA(raB);
            else              lwriteA(raA);
            lwriteW();
            __syncthreads();
        }
    }
#pragma unroll
    for (int j = 0; j < 4; ++j) {
        float4 v;
        v.x = fmaxf(acc[0][j] + b1v[j], 0.f);
        v.y = fmaxf(acc[1][j] + b1v[j], 0.f);
        v.z = fmaxf(acc[2][j] + b1v[j], 0.f);
        v.w = fmaxf(acc[3][j] + b1v[j], 0.f);
        *(float4*)&ea1T[tx * 4 + j][ty * 4] = v;
    }
    __syncthreads();

    // ---- layer 2
    int e0 = (tid >> 3) * 2;       // even
    int c0 = (tid & 7) * 4;
    float acc2[2][4] = {};
    for (int k = 0; k < 64; ++k) {
        float2 a2 = *(const float2*)&ea1T[k][e0];
        float4 w4 = *(const float4*)&w2s[k][c0];
        float w[4] = { w4.x, w4.y, w4.z, w4.w };
#pragma unroll
        for (int j = 0; j < 4; ++j) {
            acc2[0][j] += a2.x * w[j]; acc2[1][j] += a2.y * w[j];
        }
    }
#pragma unroll
    for (int r = 0; r < 2; ++r) {
        int e = e0 + r, s = srcs[e];
        const float4 xv = *(const float4*)(x + (size_t)s * 32 + c0);
        float xa[4] = { xv.x, xv.y, xv.z, xv.w };
        float4 m;
        m.x = fmaxf(xa[0] + fmaxf(acc2[r][0] + b2s[c0 + 0], 0.f), 0.f);
        m.y = fmaxf(xa[1] + fmaxf(acc2[r][1] + b2s[c0 + 1], 0.f), 0.f);
        m.z = fmaxf(xa[2] + fmaxf(acc2[r][2] + b2s[c0 + 2], 0.f), 0.f);
        m.w = fmaxf(xa[3] + fmaxf(acc2[r][3] + b2s[c0 + 3], 0.f), 0.f);
        *(float4*)(msg_sorted + (size_t)poss[e] * 32 + c0) = m;
    }
}

// ---------------------------------------------------------------- segmented sum over dst-sorted msg rows
__global__ __launch_bounds__(256) void segsum_kernel(const float* __restrict__ msg_sorted,
                                                     const int* __restrict__ offs_n,
                                                     float* __restrict__ agg)
{
    int wid  = (blockIdx.x * blockDim.x + threadIdx.x) >> 6;
    int lane = threadIdx.x & 63;
    if (wid >= BN_) return;
    int off0 = offs_n[wid], off1 = offs_n[wid + 1];
    int col = lane & 31, rr = lane >> 5;
    float sum = 0.f;
    for (int j = off0 + rr; j < off1; j += 2)
        sum += msg_sorted[(size_t)j * 32 + col];
    sum += __shfl_xor(sum, 32);
    if (lane < 32) agg[(size_t)wid * 32 + col] = sum;
}

// ---------------------------------------------------------------- 128x128 tiled GEMM, 8x8 microtile (single buffer)
template <int ACT, bool HASBIAS, bool HASA2, bool GATHER, bool SCORES, bool ATTC>
__global__ __launch_bounds__(256) void gemm_tile128(
    const float* __restrict__ A, const float* __restrict__ A2,
    const int* __restrict__ rowidx, const float* __restrict__ rowscale,
    const float* __restrict__ W, const float* __restrict__ bias,
    float* __restrict__ C, int M, int N, int K,
    const float* __restrict__ pvec, float* __restrict__ pout,
    const float* __restrict__ av_src, const float* __restrict__ av_dst,
    float* __restrict__ ao_src, float* __restrict__ ao_dst)
{
    __shared__ float As[16][132];
    __shared__ float Ws[16][132];
    int tid = threadIdx.x;
    int tx = tid & 15, ty = tid >> 4;
    int mb = blockIdx.y * 128, nb = blockIdx.x * 128;
    float acc[8][8] = {};

    int am = tid & 127;
    int ak = (tid >> 7) * 8;
    int wk = tid >> 4;
    int wn = (tid & 15) * 8;

    int   arow  = mb + am;
    float ascal = 1.f;
    if (GATHER) { ascal = rowscale[arow]; arow = rowidx[arow]; }

    for (int kt = 0; kt < K; kt += 16) {
        {
            const float* pa = A + (size_t)arow * K + kt + ak;
            float4 v0 = *(const float4*)(pa);
            float4 v1 = *(const float4*)(pa + 4);
            if (HASA2) {
                const float* pb = A2 + (size_t)arow * K + kt + ak;
                float4 u0 = *(const float4*)(pb);
                float4 u1 = *(const float4*)(pb + 4);
                v0.x += u0.x; v0.y += u0.y; v0.z += u0.z; v0.w += u0.w;
                v1.x += u1.x; v1.y += u1.y; v1.z += u1.z; v1.w += u1.w;
            }
            if (GATHER) {
                v0.x *= ascal; v0.y *= ascal; v0.z *= ascal; v0.w *= ascal;
                v1.x *= ascal; v1.y *= ascal; v1.z *= ascal; v1.w *= ascal;
            }
            As[ak + 0][am] = v0.x; As[ak + 1][am] = v0.y;
            As[ak + 2][am] = v0.z; As[ak + 3][am] = v0.w;
            As[ak + 4][am] = v1.x; As[ak + 5][am] = v1.y;
            As[ak + 6][am] = v1.z; As[ak + 7][am] = v1.w;
        }
        {
            const float* pw = W + (size_t)(kt + wk) * N + nb + wn;
            *(float4*)&Ws[wk][wn]     = *(const float4*)(pw);
            *(float4*)&Ws[wk][wn + 4] = *(const float4*)(pw + 4);
        }
        __syncthreads();
#pragma unroll
        for (int k2 = 0; k2 < 16; ++k2) {
            float4 a0 = *(const float4*)&As[k2][ty * 8];
            float4 a1 = *(const float4*)&As[k2][ty * 8 + 4];
            float4 w0 = *(const float4*)&Ws[k2][tx * 4];
            float4 w1 = *(const float4*)&Ws[k2][64 + tx * 4];
            float a[8] = { a0.x, a0.y, a0.z, a0.w, a1.x, a1.y, a1.z, a1.w };
            float w[8] = { w0.x, w0.y, w0.z, w0.w, w1.x, w1.y, w1.z, w1.w };
#pragma unroll
            for (int i = 0; i < 8; ++i)
#pragma unroll
                for (int j = 0; j < 8; ++j) acc[i][j] += a[i] * w[j];
        }
        __syncthreads();
    }
    int col0 = nb + tx * 4, col1 = nb + 64 + tx * 4;
    int hd0 = col0 >> 6, hd1 = col1 >> 6;
#pragma unroll
    for (int i = 0; i < 8; ++i) {
        int m = mb + ty * 8 + i;
        float r[8];
#pragma unroll
        for (int j = 0; j < 4; ++j) {
            float v = acc[i][j];
            if (HASBIAS) v += bias[col0 + j];
            if (ACT == 1) v = fmaxf(v, 0.f);
            r[j] = v;
        }
#pragma unroll
        for (int j = 4; j < 8; ++j) {
            float v = acc[i][j];
            if (HASBIAS) v += bias[col1 + j - 4];
            if (ACT == 1) v = fmaxf(v, 0.f);
            r[j] = v;
        }
        float4 o0 = { r[0], r[1], r[2], r[3] };
        float4 o1 = { r[4], r[5], r[6], r[7] };
        *(float4*)&C[(size_t)m * N + col0] = o0;
        *(float4*)&C[(size_t)m * N + col1] = o1;

        if (SCORES) {
            float d = 0.f;
#pragma unroll
            for (int j = 0; j < 4; ++j) d += r[j] * pvec[col0 + j];
#pragma unroll
            for (int j = 4; j < 8; ++j) d += r[j] * pvec[col1 + j - 4];
#pragma unroll
            for (int o = 1; o < 16; o <<= 1) d += __shfl_xor(d, o);
            if (tx == 0) atomicAdd(&pout[m], d);
        }
        if (ATTC) {
            float sA = 0.f, sB = 0.f, dA = 0.f, dB = 0.f;
#pragma unroll
            for (int j = 0; j < 4; ++j) {
                int w0i = hd0 * 64 + ((col0 & 63) + j);
                int w1i = hd1 * 64 + ((col1 & 63) + j);
                sA += r[j] * av_src[w0i];   dA += r[j] * av_dst[w0i];
                sB += r[j + 4] * av_src[w1i]; dB += r[j + 4] * av_dst[w1i];
            }
#pragma unroll
            for (int o = 1; o < 16; o <<= 1) {
                sA += __shfl_xor(sA, o); sB += __shfl_xor(sB, o);
                dA += __shfl_xor(dA, o); dB += __shfl_xor(dB, o);
            }
            if (tx == 0) {
                atomicAdd(&ao_src[m * 4 + hd0], sA);
                atomicAdd(&ao_src[m * 4 + hd1], sB);
                atomicAdd(&ao_dst[m * 4 + hd0], dA);
                atomicAdd(&ao_dst[m * 4 + hd1], dB);
            }
        }
    }
}

// ---------------------------------------------------------------- bitonic sort (512, descending, idx-asc tiebreak)
__device__ void bitonic_desc512(float* val, int* idx, int t) {
    for (int k = 2; k <= 512; k <<= 1) {
        for (int j = k >> 1; j > 0; j >>= 1) {
            __syncthreads();
            int ixj = t ^ j;
            if (ixj > t) {
                float v0 = val[t], v1 = val[ixj];
                int   i0 = idx[t], i1 = idx[ixj];
                bool before = (v0 > v1) || (v0 == v1 && i0 < i1);
                bool dir = ((t & k) == 0);
                bool doswap = dir ? (!before) : before;
                if (doswap) { val[t] = v1; val[ixj] = v0; idx[t] = i1; idx[ixj] = i0; }
            }
        }
    }
    __syncthreads();
}

// sorts RAW scores (tanh monotonic); applies tanh(s/norm) only to selected
__global__ __launch_bounds__(512) void topk1_kernel(const float* __restrict__ s,
                                                    const float* __restrict__ norms,
                                                    float* __restrict__ topval,
                                                    int* __restrict__ topnode,
                                                    int* __restrict__ kept,
                                                    int* __restrict__ newid)
{
    __shared__ float val[512];
    __shared__ int   idx[512];
    int b = blockIdx.x, t = threadIdx.x;
    val[t] = s[b * N_ + t]; idx[t] = t;
    bitonic_desc512(val, idx, t);
    if (t < K1_) {
        int node = b * N_ + idx[t];
        int orow = b * K1_ + t;
        topnode[orow] = node;
        topval[orow]  = tanhf(val[t] / norms[0]);
        kept[node]  = 1;
        newid[node] = orow;
    }
}

// ---------------------------------------------------------------- readout 1 (gathered): 256 blocks, 16 rowgroups
__global__ __launch_bounds__(1024) void readout1_kernel(const float* __restrict__ h,
                                                        const int* __restrict__ topnode,
                                                        const float* __restrict__ topval,
                                                        float* __restrict__ zbuf)
{
    __shared__ float rmx[1024], rsm[1024];
    int b = blockIdx.x >> 2, cg = blockIdx.x & 3;
    int tid = threadIdx.x;
    int cl = tid & 63, rg = tid >> 6;
    int c = cg * 64 + cl;
    float mx = -INFINITY, sm = 0.f;
    for (int j = rg; j < K1_; j += 16) {
        int row = topnode[b * K1_ + j];
        float v = h[(size_t)row * 256 + c] * topval[b * K1_ + j];
        mx = fmaxf(mx, v); sm += v;
    }
    rmx[tid] = mx; rsm[tid] = sm;
    __syncthreads();
    if (tid < 512) { rmx[tid] = fmaxf(rmx[tid], rmx[tid + 512]); rsm[tid] += rsm[tid + 512]; }
    __syncthreads();
    if (tid < 256) { rmx[tid] = fmaxf(rmx[tid], rmx[tid + 256]); rsm[tid] += rsm[tid + 256]; }
    __syncthreads();
    if (tid < 128) { rmx[tid] = fmaxf(rmx[tid], rmx[tid + 128]); rsm[tid] += rsm[tid + 128]; }
    __syncthreads();
    if (tid < 64) {
        zbuf[b * 512 + c]       = fmaxf(rmx[tid], rmx[tid + 64]);
        zbuf[b * 512 + 256 + c] = (rsm[tid] + rsm[tid + 64]) / (float)K1_;
    }
}

// ---------------------------------------------------------------- GAT aggregation via node-CSR + kept filter
__global__ __launch_bounds__(256) void gat_agg_kernel(const float* __restrict__ xl,
                                                      const float* __restrict__ a_src,
                                                      const float* __restrict__ a_dst,
                                                      const int* __restrict__ tnode,
                                                      const int* __restrict__ offs_n,
                                                      const int* __restrict__ csr_e,
                                                      const int* __restrict__ srcG,
                                                      const int* __restrict__ kept,
                                                      const int* __restrict__ newid,
                                                      const float* __restrict__ gat_b,
                                                      const float* __restrict__ pool2_w,
                                                      float* __restrict__ g,
                                                      float* __restrict__ s2)
{
    int wid  = (blockIdx.x * blockDim.x + threadIdx.x) >> 6;
    int lane = threadIdx.x & 63;
    if (wid >= NK_) return;
    int orig = tnode[wid];
    int off0 = offs_n[orig], off1 = offs_n[orig + 1];

    float4 ad = *(const float4*)(a_dst + (size_t)wid * 4);
    float4 asf = *(const float4*)(a_src + (size_t)wid * 4);
    float adv[4] = { ad.x, ad.y, ad.z, ad.w };
    float lsf[4] = { lrelu(asf.x + ad.x), lrelu(asf.y + ad.y),
                     lrelu(asf.z + ad.z), lrelu(asf.w + ad.w) };

    float den[4] = {};
    float acc[4] = {};
    int src_nxt = (off0 < off1) ? srcG[csr_e[off0]] : 0;
    for (int p = off0; p < off1; ++p) {
        int srcn = src_nxt;
        if (p + 1 < off1) src_nxt = srcG[csr_e[p + 1]];   // prefetch next chain
        if (!kept[srcn]) continue;       // wave-uniform branch
        int s1 = newid[srcn];
        float4 a1 = *(const float4*)(a_src + (size_t)s1 * 4);
        float av1[4] = { a1.x, a1.y, a1.z, a1.w };
#pragma unroll
        for (int r = 0; r < 4; ++r) {
            float w1 = expf(fminf(lrelu(av1[r] + adv[r]), 80.f));
            den[r] += w1;
            acc[r] += w1 * xl[(size_t)s1 * 256 + r * 64 + lane];
        }
    }
    float gv[4];
#pragma unroll
    for (int r = 0; r < 4; ++r) {
        float ws = expf(fminf(lsf[r], 80.f));
        den[r] += ws;
        acc[r] = (acc[r] + ws * xl[(size_t)wid * 256 + r * 64 + lane]) / den[r];
        int d = r * 64 + lane;
        gv[r] = fmaxf(acc[r] + gat_b[d], 0.f);
        g[(size_t)wid * 256 + d] = gv[r];
    }
    float dot = 0.f;
#pragma unroll
    for (int r = 0; r < 4; ++r) dot += gv[r] * pool2_w[r * 64 + lane];
    for (int o = 32; o > 0; o >>= 1) dot += __shfl_xor(dot, o);
    if (lane == 0) s2[wid] = dot;   // raw; tanh deferred (monotonic)
}

// ---------------------------------------------------------------- topk2 sort (64 blocks); tanh applied to selected
__global__ __launch_bounds__(512) void topk2_sort_kernel(const float* __restrict__ s2,
                                                         const float* __restrict__ norms,
                                                         int* __restrict__ t2row,
                                                         float* __restrict__ t2val)
{
    __shared__ float val[512];
    __shared__ int   idx[512];
    int b = blockIdx.x, t = threadIdx.x;
    val[t] = (t < K1_) ? s2[b * K1_ + t] : -INFINITY;
    idx[t] = t;
    bitonic_desc512(val, idx, t);
    if (t < K2_) {
        t2row[b * K2_ + t] = b * K1_ + idx[t];
        t2val[b * K2_ + t] = tanhf(val[t] / norms[1]);
    }
}

// ---------------------------------------------------------------- readout 2
__global__ __launch_bounds__(512) void readout2_kernel(const float* __restrict__ g,
                                                       const int* __restrict__ t2row,
                                                       const float* __restrict__ t2val,
                                                       float* __restrict__ zbuf)
{
    __shared__ float rmx[512], rsm[512];
    int b = blockIdx.x >> 2, cg = blockIdx.x & 3;
    int tid = threadIdx.x;
    int cl = tid & 63, rg = tid >> 6;
    int c = cg * 64 + cl;
    float mx = -INFINITY, sm = 0.f;
    for (int j = rg; j < K2_; j += 8) {
        int row = t2row[b * K2_ + j];
        float v = g[(size_t)row * 256 + c] * t2val[b * K2_ + j];
        mx = fmaxf(mx, v); sm += v;
    }
    rmx[tid] = mx; rsm[tid] = sm;
    __syncthreads();
    if (tid < 256) { rmx[tid] = fmaxf(rmx[tid], rmx[tid + 256]); rsm[tid] += rsm[tid + 256]; }
    __syncthreads();
    if (tid < 128) { rmx[tid] = fmaxf(rmx[tid], rmx[tid + 128]); rsm[tid] += rsm[tid + 128]; }
    __syncthreads();
    if (tid < 64) {
        zbuf[b * 512 + c]       += fmaxf(rmx[tid], rmx[tid + 64]);
        zbuf[b * 512 + 256 + c] += (rsm[tid] + rsm[tid + 64]) / (float)K2_;
    }
}

// ---------------------------------------------------------------- head
__global__ __launch_bounds__(128) void head_kernel(const float* __restrict__ zbuf,
                                                   const float* __restrict__ l1w, const float* __restrict__ l1b,
                                                   const float* __restrict__ l2w, const float* __restrict__ l2b,
                                                   const float* __restrict__ l3w, const float* __restrict__ l3b,
                                                   float* __restrict__ out)
{
    __shared__ float zs[512];
    __shared__ float h1s[128];
    __shared__ float h2s[64];
    __shared__ float os[2];
    int b = blockIdx.x, t = threadIdx.x;
    for (int i = t; i < 512; i += 128) zs[i] = zbuf[b * 512 + i];
    __syncthreads();
    float acc = l1b[t];
    for (int k = 0; k < 512; ++k) acc += zs[k] * l1w[k * 128 + t];
    h1s[t] = fmaxf(acc, 0.f);
    __syncthreads();
    if (t < 64) {
        float a2 = l2b[t];
        for (int k = 0; k < 128; ++k) a2 += h1s[k] * l2w[k * 64 + t];
        h2s[t] = fmaxf(a2, 0.f);
    }
    __syncthreads();
    if (t < 2) {
        float a3 = l3b[t];
        for (int k = 0; k < 64; ++k) a3 += h2s[k] * l3w[k * 2 + t];
        os[t] = a3;
    }
    __syncthreads();
    if (t == 0) {
        float m = fmaxf(os[0], os[1]);
        float lse = m + logf(expf(os[0] - m) + expf(os[1] - m));
        out[b * 2 + 0] = os[0] - lse;
        out[b * 2 + 1] = os[1] - lse;
    }
}

// ================================================================ launch
extern "C" void kernel_launch(void* const* d_in, const int* in_sizes, int n_in,
                              void* d_out, int out_size, void* d_ws, size_t ws_size,
                              hipStream_t stream)
{
    const float* x         = (const float*)d_in[0];
    const int*   eidx      = (const int*)d_in[1];
    const float* edge_attr = (const float*)d_in[3];
    const float* dec1_w    = (const float*)d_in[4];
    const float* dec1_b    = (const float*)d_in[5];
    const float* dec2_w    = (const float*)d_in[6];
    const float* dec2_b    = (const float*)d_in[7];
    const float* mlp1_w    = (const float*)d_in[8];
    const float* mlp1_b    = (const float*)d_in[9];
    const float* mlp2_w    = (const float*)d_in[10];
    const float* mlp2_b    = (const float*)d_in[11];
    const float* pool1_w   = (const float*)d_in[12];
    const float* gat_w     = (const float*)d_in[13];
    const float* att_src   = (const float*)d_in[14];
    const float* att_dst   = (const float*)d_in[15];
    const float* gat_b     = (const float*)d_in[16];
    const float* pool2_w   = (const float*)d_in[17];
    const float* lin1_w    = (const float*)d_in[18];
    const float* lin1_b    = (const float*)d_in[19];
    const float* lin2_w    = (const float*)d_in[20];
    const float* lin2_b    = (const float*)d_in[21];
    const float* lin3_w    = (const float*)d_in[22];
    const float* lin3_b    = (const float*)d_in[23];
    const int* srcG = eidx;
    const int* dstG = eidx + E_;
    float* out = (float*)d_out;

    // ---- workspace layout (zeroed prefix: cnt_node, kept, s, a_src, a_dst)
    char* base = (char*)d_ws;
    size_t o = 0;
    auto alloc = [&](size_t bytes) { size_t r = o; o = (o + bytes + 255) & ~(size_t)255; return r; };
    size_t cntn_off   = alloc((size_t)BN_ * 4);
    size_t kept_off   = alloc((size_t)BN_ * 4);
    size_t s_off      = alloc((size_t)BN_ * 4);        // scores1 accum; also s2
    size_t asrc_off   = alloc((size_t)NK_ * 4 * 4);
    size_t adst_off   = alloc((size_t)NK_ * 4 * 4);
    size_t zero_bytes = o;
    size_t agg_off    = alloc((size_t)BN_ * 32 * 4);   // overwritten by segsum (no zeroing)
    size_t newid_off  = alloc((size_t)BN_ * 4);
    size_t offsn_off  = alloc((size_t)(BN_ + 1) * 4);
    size_t pos_off    = alloc((size_t)E_ * 4);
    size_t csre_off   = alloc((size_t)E_ * 4);
    size_t h_off      = alloc((size_t)BN_ * 256 * 4);  // also g; msg_sorted aliases region
    size_t hp_off     = alloc((size_t)NK_ * 256 * 4);  // aliasing headroom for msg
    size_t xl_off     = alloc((size_t)NK_ * 256 * 4);  // also t1
    size_t tnode_off  = alloc((size_t)NK_ * 4);        // also t2row
    size_t tval_off   = alloc((size_t)NK_ * 4);        // also t2val
    size_t zbuf_off   = alloc((size_t)B_ * 512 * 4);
    size_t norm_off   = alloc(256);
    if (o > ws_size) return;

    int*   cnt_node = (int*)  (base + cntn_off);
    int*   kept     = (int*)  (base + kept_off);
    float* s        = (float*)(base + s_off);
    float* a_src    = (float*)(base + asrc_off);
    float* a_dst    = (float*)(base + adst_off);
    float* agg      = (float*)(base + agg_off);
    int*   newid    = (int*)  (base + newid_off);
    int*   offs_n   = (int*)  (base + offsn_off);
    int*   pos_e    = (int*)  (base + pos_off);
    int*   csr_e    = (int*)  (base + csre_off);
    float* h        = (float*)(base + h_off);
    float* g        = h;
    float* msg      = h;                                // [E_,32] aliases h..xl (dead before MLP1)
    float* xl       = (float*)(base + xl_off);
    float* t1       = xl;
    int*   tnode    = (int*)  (base + tnode_off);
    float* tval     = (float*)(base + tval_off);
    float* zbuf     = (float*)(base + zbuf_off);
    float* norms    = (float*)(base + norm_off);

    hipMemsetAsync(d_ws, 0, zero_bytes, stream);

    norm_kernel<<<1, 256, 0, stream>>>(pool1_w, pool2_w, norms);

    // node-CSR over ALL edges -> pos_e (inverse) + csr_e (forward)
    count_node_kernel<<<E_ / 256, 256, 0, stream>>>(dstG, cnt_node);
    scan_kernel<BN_><<<1, 1024, 0, stream>>>(cnt_node, offs_n);
    fill_node_kernel<<<E_ / 256, 256, 0, stream>>>(dstG, offs_n, cnt_node, pos_e, csr_e);

    // edge MLP in natural order (256 thr/block, R16 form), msg rows written dst-sorted
    edge_mlp_kernel<<<E_ / 64, 256, 0, stream>>>(edge_attr, srcG, pos_e, x,
                                                 dec1_w, dec1_b, dec2_w, dec2_b, msg);
    segsum_kernel<<<BN_ / 4, 256, 0, stream>>>(msg, offs_n, agg);

    // MLP1: t1 = relu((x+agg) @ mlp1_w + b)
    gemm_tile128<1, true, true, false, false, false><<<dim3(1, BN_ / 128), 256, 0, stream>>>(
        x, agg, nullptr, nullptr, mlp1_w, mlp1_b, t1, BN_, 128, 32,
        nullptr, nullptr, nullptr, nullptr, nullptr, nullptr);
    // MLP2: h = relu(t1 @ mlp2_w + b) + fused scores1 partial dots into s
    gemm_tile128<1, true, false, false, true, false><<<dim3(2, BN_ / 128), 256, 0, stream>>>(
        t1, nullptr, nullptr, nullptr, mlp2_w, mlp2_b, h, BN_, 256, 128,
        pool1_w, s, nullptr, nullptr, nullptr, nullptr);

    topk1_kernel<<<B_, 512, 0, stream>>>(s, norms, tval, tnode, kept, newid);
    readout1_kernel<<<B_ * 4, 1024, 0, stream>>>(h, tnode, tval, zbuf);

    // GAT transform with fused top-k gather + fused attcoef partials
    gemm_tile128<0, false, false, true, false, true><<<dim3(2, NK_ / 128), 256, 0, stream>>>(
        h, nullptr, tnode, tval, gat_w, nullptr, xl, NK_, 256, 256,
        nullptr, nullptr, att_src, att_dst, a_src, a_dst);

    // GAT aggregation via node-CSR + kept filter; raw s2
    gat_agg_kernel<<<NK_ / 4, 256, 0, stream>>>(xl, a_src, a_dst, tnode, offs_n, csr_e,
                                                srcG, kept, newid, gat_b, pool2_w, g, s);

    topk2_sort_kernel<<<B_, 512, 0, stream>>>(s, norms, tnode, tval);
    readout2_kernel<<<B_ * 4, 512, 0, stream>>>(g, tnode, tval, zbuf);

    head_kernel<<<B_, 128, 0, stream>>>(zbuf, lin1_w, lin1_b, lin2_w, lin2_b,
                                        lin3_w, lin3_b, out);
}